// Round 1
// baseline (136.748 us; speedup 1.0000x reference)
//
#include <hip/hip_runtime.h>

#define N_NODES 10000
#define N_EDGES 320000
#define DIN 256
#define DOUT 256

// ---------------- degree count ----------------
__global__ void count_deg_kernel(const int* __restrict__ src, int* __restrict__ deg) {
    int e = blockIdx.x * blockDim.x + threadIdx.x;
    if (e < N_EDGES) atomicAdd(&deg[src[e]], 1);
}

// ---------------- exclusive prefix scan (single block, 256 threads) ----------------
__global__ void scan_kernel(const int* __restrict__ deg, int* __restrict__ rowptr) {
    const int T = 256;
    const int per = (N_NODES + T - 1) / T;  // 40
    int tid = threadIdx.x;
    int start = tid * per;
    int sum = 0;
    for (int k = 0; k < per; ++k) {
        int idx = start + k;
        sum += (idx < N_NODES) ? deg[idx] : 0;
    }
    // inclusive wave scan of per-thread sums
    int lane = tid & 63;
    int wid = tid >> 6;
    int x = sum;
    for (int off = 1; off < 64; off <<= 1) {
        int y = __shfl_up(x, off, 64);
        if (lane >= off) x += y;
    }
    __shared__ int wsum[4];
    __shared__ int wbase[4];
    if (lane == 63) wsum[wid] = x;
    __syncthreads();
    if (tid == 0) {
        int acc = 0;
        for (int w = 0; w < 4; ++w) { wbase[w] = acc; acc += wsum[w]; }
    }
    __syncthreads();
    int excl = x - sum + wbase[wid];  // exclusive prefix for this thread's chunk
    int run = excl;
    for (int k = 0; k < per; ++k) {
        int idx = start + k;
        if (idx < N_NODES) {
            rowptr[idx] = run;
            run += deg[idx];
        }
    }
    if (tid == T - 1) rowptr[N_NODES] = run;  // == N_EDGES
}

// ---------------- d_inv = 1/sqrt(deg) ----------------
__global__ void dinv_kernel(const int* __restrict__ deg, float* __restrict__ d_inv) {
    int i = blockIdx.x * blockDim.x + threadIdx.x;
    if (i < N_NODES) d_inv[i] = 1.0f / sqrtf((float)deg[i]);
}

// ---------------- CSR fill ----------------
__global__ void fill_csr_kernel(const int* __restrict__ src, const int* __restrict__ dst,
                                const int* __restrict__ rowptr, int* __restrict__ cursor,
                                int* __restrict__ col) {
    int e = blockIdx.x * blockDim.x + threadIdx.x;
    if (e < N_EDGES) {
        int s = src[e];
        int p = atomicAdd(&cursor[s], 1);
        col[rowptr[s] + p] = dst[e];
    }
}

// ---------------- aggregation: agg[i] = d_inv[i]*(sum_j d_inv[j]*x[j] + d_inv[i]*x[i]) ----
__global__ __launch_bounds__(256) void aggregate_kernel(
    const float* __restrict__ x, const float* __restrict__ d_inv,
    const int* __restrict__ rowptr, const int* __restrict__ col,
    float* __restrict__ agg) {
    __shared__ int cols_s[256];
    __shared__ float dv_s[256];
    int i = blockIdx.x;
    int c = threadIdx.x;
    float di = d_inv[i];
    float acc = di * x[i * DIN + c];  // self-loop term (before final d_inv[i] scale)
    int beg = rowptr[i], end = rowptr[i + 1];
    for (int k0 = beg; k0 < end; k0 += 256) {
        __syncthreads();
        int kk = k0 + c;
        if (kk < end) {
            int j = col[kk];
            cols_s[c] = j;
            dv_s[c] = d_inv[j];
        }
        __syncthreads();
        int cnt = min(256, end - k0);
        for (int t = 0; t < cnt; ++t) {
            int j = cols_s[t];
            acc += dv_s[t] * x[j * DIN + c];
        }
    }
    agg[i * DIN + c] = di * acc;
}

// ---------------- GEMM 64x64 tile + bias + relu: out = relu(agg @ W + b) ----------------
__global__ __launch_bounds__(256) void gemm_bias_relu_kernel(
    const float* __restrict__ A, const float* __restrict__ W,
    const float* __restrict__ bias, float* __restrict__ out) {
    __shared__ float a_lds[16][64];  // [k][row]
    __shared__ float b_lds[16][64];  // [k][col]
    const int tid = threadIdx.x;
    const int tx = tid & 15, ty = tid >> 4;
    const int col0 = blockIdx.x * 64;
    const int row0 = blockIdx.y * 64;

    const int ar = tid >> 2;          // 0..63: A row within tile
    const int ak = (tid & 3) * 4;     // 0,4,8,12: A k offset
    const int bk = tid >> 4;          // 0..15: B k
    const int bc = (tid & 15) * 4;    // B col offset

    float acc[4][4] = {};

    for (int k0 = 0; k0 < DIN; k0 += 16) {
        int arow = row0 + ar;
        float4 av4 = make_float4(0.f, 0.f, 0.f, 0.f);
        if (arow < N_NODES) av4 = *(const float4*)&A[arow * DIN + k0 + ak];
        float4 bv4 = *(const float4*)&W[(k0 + bk) * DOUT + col0 + bc];
        __syncthreads();
        a_lds[ak + 0][ar] = av4.x;
        a_lds[ak + 1][ar] = av4.y;
        a_lds[ak + 2][ar] = av4.z;
        a_lds[ak + 3][ar] = av4.w;
        *(float4*)&b_lds[bk][bc] = bv4;
        __syncthreads();
#pragma unroll
        for (int k = 0; k < 16; ++k) {
            float4 av = *(const float4*)&a_lds[k][ty * 4];
            float4 bv = *(const float4*)&b_lds[k][tx * 4];
            float a[4] = {av.x, av.y, av.z, av.w};
            float b4[4] = {bv.x, bv.y, bv.z, bv.w};
#pragma unroll
            for (int r = 0; r < 4; ++r)
#pragma unroll
                for (int c = 0; c < 4; ++c)
                    acc[r][c] += a[r] * b4[c];
        }
    }

#pragma unroll
    for (int r = 0; r < 4; ++r) {
        int row = row0 + ty * 4 + r;
        if (row < N_NODES) {
            float4 v;
            v.x = fmaxf(acc[r][0] + bias[col0 + tx * 4 + 0], 0.f);
            v.y = fmaxf(acc[r][1] + bias[col0 + tx * 4 + 1], 0.f);
            v.z = fmaxf(acc[r][2] + bias[col0 + tx * 4 + 2], 0.f);
            v.w = fmaxf(acc[r][3] + bias[col0 + tx * 4 + 3], 0.f);
            *(float4*)&out[row * DOUT + col0 + tx * 4] = v;
        }
    }
}

extern "C" void kernel_launch(void* const* d_in, const int* in_sizes, int n_in,
                              void* d_out, int out_size, void* d_ws, size_t ws_size,
                              hipStream_t stream) {
    const float* x = (const float*)d_in[0];
    const int* edge_index = (const int*)d_in[1];
    const float* W = (const float*)d_in[2];
    const float* b = (const float*)d_in[3];
    float* out = (float*)d_out;

    const int* src = edge_index;            // edge_index[0, :]
    const int* dst = edge_index + N_EDGES;  // edge_index[1, :]

    char* ws = (char*)d_ws;
    // workspace layout (bytes)
    int* deg    = (int*)(ws + 0);          // 40000
    int* cursor = (int*)(ws + 40000);      // 40000  (deg+cursor zeroed together)
    int* rowptr = (int*)(ws + 80000);      // 40004
    float* dinv = (float*)(ws + 120320);   // 40000
    int* col    = (int*)(ws + 160512);     // 1280000
    float* agg  = (float*)(ws + 1440768);  // 10240000; total ~11.7 MB

    hipMemsetAsync(ws, 0, 80000, stream);  // deg + cursor

    count_deg_kernel<<<(N_EDGES + 255) / 256, 256, 0, stream>>>(src, deg);
    scan_kernel<<<1, 256, 0, stream>>>(deg, rowptr);
    dinv_kernel<<<(N_NODES + 255) / 256, 256, 0, stream>>>(deg, dinv);
    fill_csr_kernel<<<(N_EDGES + 255) / 256, 256, 0, stream>>>(src, dst, rowptr, cursor, col);
    aggregate_kernel<<<N_NODES, 256, 0, stream>>>(x, dinv, rowptr, col, agg);
    gemm_bias_relu_kernel<<<dim3(DOUT / 64, (N_NODES + 63) / 64), 256, 0, stream>>>(agg, W, b, out);
}